// Round 4
// baseline (815.873 us; speedup 1.0000x reference)
//
#include <hip/hip_runtime.h>
#include <stdint.h>

#define NB 4
#define CC 64
#define VV 8192
#define KB 64
#define NCHUNK (VV / KB)     // 128

typedef float  f32x4 __attribute__((ext_vector_type(4)));
typedef uint32_t u32x4 __attribute__((ext_vector_type(4)));
typedef __bf16 bf16x8 __attribute__((ext_vector_type(8)));

__device__ __forceinline__ uint32_t pkbf(float a, float b) {
    union { __bf16 h[2]; uint32_t u; } t;
    t.h[0] = (__bf16)a; t.h[1] = (__bf16)b;
    return t.u;
}

// K1: y[n,c,v] = b[c] + sum_c' W[c,c'] x[n,c',v], written to global in MFMA
// A-operand FRAGMENT layout so k_main can load it with coalesced dwordx4:
// yfrag u32 index = (((n*128 + t)*4 + ct)*2 + s)*256 + lane*4 + u
//   where v = t*64 + s*32 + h*16 + kq + j, lane = (kq/4)*16 + (c&15),
//   ct = c>>4, u = h*2 + (j>>1); u32 packs (v, v+1) for even v.
__global__ __launch_bounds__(256) void k_y(const float* __restrict__ x,
                                           const float* __restrict__ Wg,
                                           const float* __restrict__ bg,
                                           uint32_t* __restrict__ yfrag) {
    const int bid  = blockIdx.x;          // 4 n x 4 cg x 16 slab = 256 blocks
    const int n    = bid >> 6;
    const int cg   = (bid >> 4) & 3;
    const int slab = bid & 15;
    const int vp   = slab * 256 + threadIdx.x;   // 0..4095 (v-pair)
    const int v    = vp * 2;
    const float* xg = x + (size_t)n * CC * VV + v;

    float a0[16], a1[16];
    #pragma unroll
    for (int i = 0; i < 16; ++i) { float bb = bg[cg * 16 + i]; a0[i] = bb; a1[i] = bb; }

    #pragma unroll 4
    for (int cp = 0; cp < CC; ++cp) {
        float2 xv = *(const float2*)(xg + (size_t)cp * VV);
        #pragma unroll
        for (int i = 0; i < 16; ++i) {
            float w = Wg[(cg * 16 + i) * CC + cp];   // uniform -> scalar load
            a0[i] += w * xv.x;
            a1[i] += w * xv.y;
        }
    }
    const int t  = v >> 6;
    const int s  = (v >> 5) & 1;
    const int kk = v & 31;
    const int g  = (kk >> 2) & 3;        // k-group (kq = g*4)
    const int j  = kk & 3;               // even
    const int h  = kk >> 4;
    const int u  = h * 2 + (j >> 1);
    uint32_t* base = yfrag + ((((size_t)n * NCHUNK + t) * 4 + cg) * 2 + s) * 256 + u;
    #pragma unroll
    for (int i = 0; i < 16; ++i)
        base[(g * 16 + i) * 4] = pkbf(a0[i], a1[i]);
}

// K2: barrier-free, LDS-free. Block = 512 thr = 8 waves = 4 w-tiles x 2 c-halves.
// Wave loads A directly in B-fragment layout (regs double as copy source),
// y from the fragment-layout global buffer (L2/L3-resident).
__global__ __launch_bounds__(512, 4) void k_main(const float* __restrict__ A,
                                                 const uint32_t* __restrict__ yfrag,
                                                 float* __restrict__ out,
                                                 float* __restrict__ Acopy,
                                                 int skipTail) {
    const int tid  = threadIdx.x;
    const int n    = blockIdx.x >> 7;
    const int w0   = (blockIdx.x & 127) * 64;
    const int lane = tid & 63;
    const int wv   = tid >> 6;
    const int wt   = wv & 3;            // w-tile (16 cols)
    const int ch   = wv >> 2;           // c-half (32 rows of out)
    const int l15  = lane & 15;
    const int g    = lane >> 4;
    const int kq   = g * 4;

    const size_t CH = (size_t)KB * VV;  // chunk row stride (floats)
    const size_t laneoff = (size_t)kq * VV + w0 + wt * 16 + l15;
    const float* pA = A     + (size_t)n * VV * VV + laneoff;
    float*       pC = Acopy + (size_t)n * VV * VV + (size_t)ch * 16 * VV + laneoff;
    const uint32_t* pY = yfrag + ((size_t)n * NCHUNK * 4 + ch * 2) * 2 * 256 + lane * 4;

    f32x4 acc[2] = {{0.f,0.f,0.f,0.f}, {0.f,0.f,0.f,0.f}};
    float ac[16], an[16];               // static double-buffered A regs
    u32x4 yf[2][2];

    auto aload = [&](float (&R)[16], const float* P) {
        #pragma unroll
        for (int s = 0; s < 2; ++s)
            #pragma unroll
            for (int h = 0; h < 2; ++h)
                #pragma unroll
                for (int j = 0; j < 4; ++j)
                    R[s * 8 + h * 4 + j] = P[(size_t)(s * 32 + h * 16 + j) * VV];
    };
    auto yload = [&](const uint32_t* P) {
        #pragma unroll
        for (int ci = 0; ci < 2; ++ci)
            #pragma unroll
            for (int s = 0; s < 2; ++s)
                yf[ci][s] = *(const u32x4*)(P + (ci * 2 + s) * 256);
    };
    auto cvt_mma = [&](const float (&R)[16]) {
        u32x4 bf[2];
        #pragma unroll
        for (int s = 0; s < 2; ++s) {
            bf[s].x = pkbf(R[s*8+0], R[s*8+1]);
            bf[s].y = pkbf(R[s*8+2], R[s*8+3]);
            bf[s].z = pkbf(R[s*8+4], R[s*8+5]);
            bf[s].w = pkbf(R[s*8+6], R[s*8+7]);
        }
        #pragma unroll
        for (int ci = 0; ci < 2; ++ci)
            #pragma unroll
            for (int s = 0; s < 2; ++s)
                acc[ci] = __builtin_amdgcn_mfma_f32_16x16x32_bf16(
                    __builtin_bit_cast(bf16x8, yf[ci][s]),
                    __builtin_bit_cast(bf16x8, bf[s]), acc[ci], 0, 0, 0);
    };
    auto cstore = [&](const float (&R)[16], float* P, bool skip) {
        if (!skip) {
            #pragma unroll
            for (int s = 0; s < 2; ++s)
                #pragma unroll
                for (int j = 0; j < 4; ++j)
                    __builtin_nontemporal_store(R[s * 8 + ch * 4 + j],
                                                P + (size_t)(s * 32 + j) * VV);
        }
    };

    aload(ac, pA);
    yload(pY);
    for (int t = 0; t < NCHUNK; t += 2) {
        const bool sk0 = skipTail && n == 3 && t >= 126;
        const bool sk1 = skipTail && n == 3 && t + 1 >= 126;
        aload(an, pA + CH);                     // prefetch t+1 (HBM)
        cvt_mma(ac);                            // chunk t
        pY += 2048; yload(pY);                  // y(t+1) before stores
        cstore(ac, pC, sk0);
        pA += 2 * CH;
        if (t + 2 < NCHUNK) aload(ac, pA);      // prefetch t+2
        cvt_mma(an);                            // chunk t+1
        if (t + 2 < NCHUNK) { pY += 2048; yload(pY); }
        cstore(an, pC + CH, sk1);
        pC += 2 * CH;
    }

    // epilogue: D layout col=lane&15 (w), row=(lane>>4)*4+r (c)  [m89/m91]
    float* po = out + (size_t)n * CC * VV + w0 + wt * 16 + l15;
    #pragma unroll
    for (int ci = 0; ci < 2; ++ci)
        #pragma unroll
        for (int r = 0; r < 4; ++r)
            po[(size_t)((ch * 2 + ci) * 16 + g * 4 + r) * VV] = acc[ci][r];
}

// K3 (only in tail-fallback mode): copy the A rows whose Acopy slots held y
__global__ __launch_bounds__(256) void k_tailcopy(const float* __restrict__ A,
                                                  float* __restrict__ Acopy,
                                                  size_t baseFloats, size_t count4) {
    size_t i = (size_t)blockIdx.x * 256 + threadIdx.x;
    if (i < count4) {
        f32x4 v = *(const f32x4*)(A + baseFloats + i * 4);
        *(f32x4*)(Acopy + baseFloats + i * 4) = v;
    }
}

extern "C" void kernel_launch(void* const* d_in, const int* in_sizes, int n_in,
                              void* d_out, int out_size, void* d_ws, size_t ws_size,
                              hipStream_t stream) {
    (void)in_sizes; (void)n_in; (void)out_size;
    const float* x = (const float*)d_in[0];
    const float* A = (const float*)d_in[1];
    const float* W = (const float*)d_in[2];
    const float* b = (const float*)d_in[3];
    float* out   = (float*)d_out;
    float* Acopy = out + (size_t)NB * CC * VV;

    const size_t yElems = (size_t)NB * NCHUNK * CC * KB;   // 2,097,152 bf16 = 4 MB
    uint32_t* yfrag;
    int skipTail = 0;
    if (ws_size >= yElems * 2) {
        yfrag = (uint32_t*)d_ws;
    } else {
        skipTail = 1;  // park y in the tail of the A-copy region (rows A[3][8064:])
        yfrag = (uint32_t*)(Acopy + ((size_t)NB * VV * VV - yElems / 2));
    }

    hipLaunchKernelGGL(k_y,    dim3(256), dim3(256), 0, stream, x, W, b, yfrag);
    hipLaunchKernelGGL(k_main, dim3(NB * 128), dim3(512), 0, stream, A, yfrag, out, Acopy, skipTail);
    if (skipTail) {
        size_t base = (size_t)NB * VV * VV - yElems / 2;     // floats
        hipLaunchKernelGGL(k_tailcopy, dim3((unsigned)((yElems / 8 + 255) / 256)), dim3(256),
                           0, stream, A, Acopy, base, yElems / 8);
    }
}

// Round 5
// 382.945 us; speedup vs baseline: 2.1305x; 2.1305x over previous
//
#include <hip/hip_runtime.h>
#include <stdint.h>

#define NB 4
#define CC 64
#define VV 8192
#define WBK 128              // w-columns per block
#define KB 64                // v per K-chunk
#define NCHUNK (VV / KB)     // 128

typedef float  f32x4 __attribute__((ext_vector_type(4)));
typedef uint32_t u32x2 __attribute__((ext_vector_type(2)));
typedef uint32_t u32x4 __attribute__((ext_vector_type(4)));
typedef __bf16 bf16x8 __attribute__((ext_vector_type(8)));

// XOR-swizzled index into a [row][KB] bf16 tile.
// g = ((v>>3) ^ row ^ (row>>2)) & 7 : verified (R2 passed) — <=4-way on the
// float4 stage-write pattern, 2-way (free, m136) on the mkfrag read pattern.
__device__ __forceinline__ int swz_idx(int row, int v) {
    int g = ((v >> 3) ^ row ^ (row >> 2)) & 7;
    return row * KB + (g << 3) + (v & 7);
}

__device__ __forceinline__ uint32_t pkbf(float a, float b) {
    union { __bf16 h[2]; uint32_t u; } t;
    t.h[0] = (__bf16)a; t.h[1] = (__bf16)b;
    return t.u;
}

__device__ __forceinline__ bf16x8 mkfrag(const __bf16* p, int row, int k0) {
    u32x2 lo = *(const u32x2*)(p + swz_idx(row, k0));
    u32x2 hi = *(const u32x2*)(p + swz_idx(row, k0 + 16));
    u32x4 u; u.x = lo.x; u.y = lo.y; u.z = hi.x; u.w = hi.y;
    return __builtin_bit_cast(bf16x8, u);
}

// K1: y[n,c,v] = b[c] + sum_c' W[c,c'] x[n,c',v], stored bf16 pre-swizzled
// in the exact LDS image k_main copies: [n][chunk t][c][swz(v&63)].
// 256 blocks x 256 thr: thread = one v-PAIR (u32 packed stores), 16 c's.
__global__ __launch_bounds__(256) void k_y(const float* __restrict__ x,
                                           const float* __restrict__ Wg,
                                           const float* __restrict__ bg,
                                           __bf16* __restrict__ yws) {
    const int bid  = blockIdx.x;           // 4 n x 4 cg x 16 slab
    const int n    = bid >> 6;
    const int cg   = (bid >> 4) & 3;
    const int slab = bid & 15;
    const int vp   = slab * 256 + threadIdx.x;   // 0..4095
    const int v    = vp * 2;
    const float* xg = x + (size_t)n * CC * VV + v;

    float a0[16], a1[16];
    #pragma unroll
    for (int i = 0; i < 16; ++i) { float bb = bg[cg * 16 + i]; a0[i] = bb; a1[i] = bb; }

    #pragma unroll 4
    for (int cp = 0; cp < CC; ++cp) {
        float2 xv = *(const float2*)(xg + (size_t)cp * VV);
        #pragma unroll
        for (int i = 0; i < 16; ++i) {
            float w = Wg[(cg * 16 + i) * CC + cp];   // uniform -> scalar load
            a0[i] += w * xv.x;
            a1[i] += w * xv.y;
        }
    }
    const int t  = v >> 6;
    const int vv = v & 63;                 // even -> u32-aligned swz slot
    __bf16* ydst = yws + (size_t)(n * NCHUNK + t) * CC * KB;
    #pragma unroll
    for (int i = 0; i < 16; ++i)
        *(uint32_t*)&ydst[swz_idx(cg * 16 + i, vv)] = pkbf(a0[i], a1[i]);
}

// K2: per block (n, w0): out[n, 0:64, w0:w0+128] = y @ A, fused A -> Acopy.
// dwordx4 staging (4 ld + 4 st + 1 y-ld per thread per chunk); chunk t's
// Acopy store issues at phase-t START (data in static double regs) so it
// drains under compute, not at the barrier.
__global__ __launch_bounds__(512, 1) void k_main(const float* __restrict__ A,
                                                 const __bf16* __restrict__ yws,
                                                 float* __restrict__ out,
                                                 float* __restrict__ Acopy,
                                                 int skipTail) {
    __shared__ __attribute__((aligned(16))) __bf16 a_sh[2][WBK * KB];  // 16KB x2
    __shared__ __attribute__((aligned(16))) __bf16 y_sh[2][CC * KB];   //  8KB x2

    const int tid = threadIdx.x;
    const int n   = blockIdx.x >> 6;
    const int w0  = (blockIdx.x & 63) * WBK;

    const int wq = tid & 31;         // w-quad (4 consecutive w)
    const int rg = tid >> 5;         // v row-group (4 consecutive v), 0..15

    const float* pA = A     + (size_t)n * VV * VV + (size_t)rg * 4 * VV + w0 + 4 * wq;
    float*       pC = Acopy + (size_t)n * VV * VV + (size_t)rg * 4 * VV + w0 + 4 * wq;
    const uint4* ysrc = (const uint4*)(yws + (size_t)n * NCHUNK * CC * KB);

    const int lane = tid & 63;
    const int wv   = tid >> 6;
    const int mrow = wv >> 2;        // 0..1 -> c-half
    const int ncol = wv & 3;         // 0..3 -> w 32-slice
    const int l15  = lane & 15;
    const int kq   = (lane >> 4) * 4;
    const int crow = mrow * 32 + l15;
    const int wcol = ncol * 32 + l15;

    f32x4 acc[2][2];
    #pragma unroll
    for (int i = 0; i < 2; ++i)
        #pragma unroll
        for (int j = 0; j < 2; ++j) acc[i][j] = (f32x4){0.f, 0.f, 0.f, 0.f};

    f32x4 ra[4], rb[4];              // static double-buffered stage regs
    uint4 yra, yrb;

    auto gload = [&](f32x4 (&R)[4], uint4& Y, int tt) {
        #pragma unroll
        for (int i = 0; i < 4; ++i)
            R[i] = *(const f32x4*)(pA + (size_t)(tt * KB + i) * VV);
        Y = ysrc[(size_t)tt * 512 + tid];
    };
    auto gstore = [&](const f32x4 (&R)[4], int tt) {
        if (skipTail && n == 3 && tt >= 126) return;
        #pragma unroll
        for (int i = 0; i < 4; ++i)
            *(f32x4*)(pC + (size_t)(tt * KB + i) * VV) = R[i];
    };
    auto ldsw = [&](const f32x4 (&R)[4], const uint4& Y, int b) {
        #pragma unroll
        for (int j = 0; j < 4; ++j) {
            u32x2 val;
            val.x = pkbf(R[0][j], R[1][j]);
            val.y = pkbf(R[2][j], R[3][j]);
            *(u32x2*)&a_sh[b][swz_idx(4 * wq + j, rg * 4)] = val;
        }
        *(uint4*)&y_sh[b][tid * 8] = Y;
    };
    auto compute = [&](int b) {
        const __bf16* ysh = y_sh[b];
        const __bf16* ash = a_sh[b];
        #pragma unroll
        for (int s = 0; s < 2; ++s) {
            const int k0 = s * 32 + kq;
            bf16x8 a0 = mkfrag(ysh, crow,      k0);
            bf16x8 a1 = mkfrag(ysh, crow + 16, k0);
            bf16x8 b0 = mkfrag(ash, wcol,      k0);
            bf16x8 b1 = mkfrag(ash, wcol + 16, k0);
            acc[0][0] = __builtin_amdgcn_mfma_f32_16x16x32_bf16(a0, b0, acc[0][0], 0, 0, 0);
            acc[0][1] = __builtin_amdgcn_mfma_f32_16x16x32_bf16(a0, b1, acc[0][1], 0, 0, 0);
            acc[1][0] = __builtin_amdgcn_mfma_f32_16x16x32_bf16(a1, b0, acc[1][0], 0, 0, 0);
            acc[1][1] = __builtin_amdgcn_mfma_f32_16x16x32_bf16(a1, b1, acc[1][1], 0, 0, 0);
        }
    };

    // prologue: chunk0 -> ra -> LDS buf0; chunk1 -> rb (stays in regs)
    gload(ra, yra, 0);
    gload(rb, yrb, 1);
    ldsw(ra, yra, 0);
    __syncthreads();

    for (int t = 0; t < NCHUNK; t += 2) {
        // even phase: compute chunk t (buf0); ra holds chunk t data
        gstore(ra, t);                            // store-early: drains under compute
        if (t + 2 < NCHUNK) gload(ra, yra, t + 2);
        compute(0);
        ldsw(rb, yrb, 1);                         // chunk t+1 image
        __syncthreads();
        // odd phase: compute chunk t+1 (buf1); rb holds chunk t+1 data
        gstore(rb, t + 1);
        if (t + 3 < NCHUNK) gload(rb, yrb, t + 3);
        compute(1);
        if (t + 2 < NCHUNK) ldsw(ra, yra, 0);     // chunk t+2 image
        __syncthreads();
    }

    // epilogue: D layout col=lane&15, row=(lane>>4)*4+r  [verified m89/m91]
    float* po = out + (size_t)n * CC * VV + w0;
    #pragma unroll
    for (int mt = 0; mt < 2; ++mt)
        #pragma unroll
        for (int nt = 0; nt < 2; ++nt)
            #pragma unroll
            for (int r = 0; r < 4; ++r) {
                int c = mrow * 32 + mt * 16 + kq + r;
                int w = ncol * 32 + nt * 16 + l15;
                po[(size_t)c * VV + w] = acc[mt][nt][r];
            }
}

// K3 (only in tail-fallback mode): copy the A rows whose Acopy slots held y
__global__ __launch_bounds__(256) void k_tailcopy(const float* __restrict__ A,
                                                  float* __restrict__ Acopy,
                                                  size_t baseFloats, size_t count4) {
    size_t i = (size_t)blockIdx.x * 256 + threadIdx.x;
    if (i < count4) {
        f32x4 v = *(const f32x4*)(A + baseFloats + i * 4);
        *(f32x4*)(Acopy + baseFloats + i * 4) = v;
    }
}

extern "C" void kernel_launch(void* const* d_in, const int* in_sizes, int n_in,
                              void* d_out, int out_size, void* d_ws, size_t ws_size,
                              hipStream_t stream) {
    (void)in_sizes; (void)n_in; (void)out_size;
    const float* x = (const float*)d_in[0];
    const float* A = (const float*)d_in[1];
    const float* W = (const float*)d_in[2];
    const float* b = (const float*)d_in[3];
    float* out   = (float*)d_out;
    float* Acopy = out + (size_t)NB * CC * VV;

    const size_t yElems = (size_t)NB * NCHUNK * CC * KB;   // 2,097,152 bf16 = 4 MB
    __bf16* yws;
    int skipTail = 0;
    if (ws_size >= yElems * 2) {
        yws = (__bf16*)d_ws;
    } else {
        skipTail = 1;  // park y in the tail of the A-copy region (rows A[3][8064:])
        yws = (__bf16*)(Acopy + ((size_t)NB * VV * VV - yElems / 2));
    }

    hipLaunchKernelGGL(k_y,    dim3(256),     dim3(256), 0, stream, x, W, b, yws);
    hipLaunchKernelGGL(k_main, dim3(NB * 64), dim3(512), 0, stream, A, yws, out, Acopy, skipTail);
    if (skipTail) {
        size_t base = (size_t)NB * VV * VV - yElems / 2;     // floats
        hipLaunchKernelGGL(k_tailcopy, dim3((unsigned)((yElems / 8 + 255) / 256)), dim3(256),
                           0, stream, A, Acopy, base, yElems / 8);
    }
}

// Round 7
// 360.706 us; speedup vs baseline: 2.2619x; 1.0617x over previous
//
#include <hip/hip_runtime.h>
#include <stdint.h>

#define NB 4
#define CC 64
#define VV 8192
#define WBK 128              // w-columns per block
#define KB 64                // v per K-chunk
#define NCHUNK (VV / KB)     // 128

typedef float  f32x4 __attribute__((ext_vector_type(4)));
typedef uint32_t u32x2 __attribute__((ext_vector_type(2)));
typedef uint32_t u32x4 __attribute__((ext_vector_type(4)));
typedef __bf16 bf16x8 __attribute__((ext_vector_type(8)));

// XOR-swizzled index into a [row][KB] bf16 tile.
// g = ((v>>3) ^ row ^ (row>>2)) & 7 : verified (R2/R5 passed) — <=4-way on
// the float4 stage-write pattern, 2-way (free, m136) on the mkfrag reads.
__device__ __forceinline__ int swz_idx(int row, int v) {
    int g = ((v >> 3) ^ row ^ (row >> 2)) & 7;
    return row * KB + (g << 3) + (v & 7);
}

__device__ __forceinline__ uint32_t pkbf(float a, float b) {
    union { __bf16 h[2]; uint32_t u; } t;
    t.h[0] = (__bf16)a; t.h[1] = (__bf16)b;
    return t.u;
}

__device__ __forceinline__ bf16x8 mkfrag(const __bf16* p, int row, int k0) {
    u32x2 lo = *(const u32x2*)(p + swz_idx(row, k0));
    u32x2 hi = *(const u32x2*)(p + swz_idx(row, k0 + 16));
    u32x4 u; u.x = lo.x; u.y = lo.y; u.z = hi.x; u.w = hi.y;
    return __builtin_bit_cast(bf16x8, u);
}

// K1: y[n,c,v] = b[c] + sum_c' W[c,c'] x[n,c',v], stored bf16 pre-swizzled
// in the exact LDS image k_main copies: [n][chunk t][c][swz(v&63)].
// 512 blocks (2/CU) x 256 thr: thread = one v-PAIR, 8 c's.
__global__ __launch_bounds__(256) void k_y(const float* __restrict__ x,
                                           const float* __restrict__ Wg,
                                           const float* __restrict__ bg,
                                           __bf16* __restrict__ yws) {
    const int bid  = blockIdx.x;           // 4 n x 8 cg x 16 slab
    const int n    = bid >> 7;
    const int cg   = (bid >> 4) & 7;       // c-group of 8
    const int slab = bid & 15;
    const int vp   = slab * 256 + threadIdx.x;   // 0..4095
    const int v    = vp * 2;
    const float* xg = x + (size_t)n * CC * VV + v;

    float a0[8], a1[8];
    #pragma unroll
    for (int i = 0; i < 8; ++i) { float bb = bg[cg * 8 + i]; a0[i] = bb; a1[i] = bb; }

    #pragma unroll 4
    for (int cp = 0; cp < CC; ++cp) {
        float2 xv = *(const float2*)(xg + (size_t)cp * VV);
        #pragma unroll
        for (int i = 0; i < 8; ++i) {
            float w = Wg[(cg * 8 + i) * CC + cp];   // uniform -> scalar load
            a0[i] += w * xv.x;
            a1[i] += w * xv.y;
        }
    }
    const int t  = v >> 6;
    const int vv = v & 63;                 // even -> u32-aligned swz slot
    __bf16* ydst = yws + (size_t)(n * NCHUNK + t) * CC * KB;
    #pragma unroll
    for (int i = 0; i < 8; ++i)
        *(uint32_t*)&ydst[swz_idx(cg * 8 + i, vv)] = pkbf(a0[i], a1[i]);
}

// K2: R5 structure verbatim (green at 383us): per block (n, w0):
// out[n, 0:64, w0:w0+128] = y @ A, fused A -> Acopy. dwordx4 staging,
// store-early, 1 chunk per barrier phase. Only delta vs R5: nontemporal
// hints on the streamed A reads / Acopy writes (read-once/write-once;
// keep L2 for the 256x-reused 4MB y image).
__global__ __launch_bounds__(512, 1) void k_main(const float* __restrict__ A,
                                                 const __bf16* __restrict__ yws,
                                                 float* __restrict__ out,
                                                 float* __restrict__ Acopy,
                                                 int skipTail) {
    __shared__ __attribute__((aligned(16))) __bf16 a_sh[2][WBK * KB];  // 16KB x2
    __shared__ __attribute__((aligned(16))) __bf16 y_sh[2][CC * KB];   //  8KB x2

    const int tid = threadIdx.x;
    const int n   = blockIdx.x >> 6;
    const int w0  = (blockIdx.x & 63) * WBK;

    const int wq = tid & 31;         // w-quad (4 consecutive w)
    const int rg = tid >> 5;         // v row-group (4 consecutive v), 0..15

    const float* pA = A     + (size_t)n * VV * VV + (size_t)rg * 4 * VV + w0 + 4 * wq;
    float*       pC = Acopy + (size_t)n * VV * VV + (size_t)rg * 4 * VV + w0 + 4 * wq;
    const uint4* ysrc = (const uint4*)(yws + (size_t)n * NCHUNK * CC * KB);

    const int lane = tid & 63;
    const int wv   = tid >> 6;
    const int mrow = wv >> 2;        // 0..1 -> c-half
    const int ncol = wv & 3;         // 0..3 -> w 32-slice
    const int l15  = lane & 15;
    const int kq   = (lane >> 4) * 4;
    const int crow = mrow * 32 + l15;
    const int wcol = ncol * 32 + l15;

    f32x4 acc[2][2];
    #pragma unroll
    for (int i = 0; i < 2; ++i)
        #pragma unroll
        for (int j = 0; j < 2; ++j) acc[i][j] = (f32x4){0.f, 0.f, 0.f, 0.f};

    f32x4 ra[4], rb[4];              // static double-buffered stage regs
    uint4 yra, yrb;

    auto gload = [&](f32x4 (&R)[4], uint4& Y, int tt) {
        #pragma unroll
        for (int i = 0; i < 4; ++i)
            R[i] = __builtin_nontemporal_load(
                (const f32x4*)(pA + (size_t)(tt * KB + i) * VV));
        Y = ysrc[(size_t)tt * 512 + tid];
    };
    auto gstore = [&](const f32x4 (&R)[4], int tt) {
        if (skipTail && n == 3 && tt >= 126) return;
        #pragma unroll
        for (int i = 0; i < 4; ++i)
            __builtin_nontemporal_store(R[i],
                (f32x4*)(pC + (size_t)(tt * KB + i) * VV));
    };
    auto ldsw = [&](const f32x4 (&R)[4], const uint4& Y, int b) {
        #pragma unroll
        for (int j = 0; j < 4; ++j) {
            u32x2 val;
            val.x = pkbf(R[0][j], R[1][j]);
            val.y = pkbf(R[2][j], R[3][j]);
            *(u32x2*)&a_sh[b][swz_idx(4 * wq + j, rg * 4)] = val;
        }
        *(uint4*)&y_sh[b][tid * 8] = Y;
    };
    auto compute = [&](int b) {
        const __bf16* ysh = y_sh[b];
        const __bf16* ash = a_sh[b];
        #pragma unroll
        for (int s = 0; s < 2; ++s) {
            const int k0 = s * 32 + kq;
            bf16x8 a0 = mkfrag(ysh, crow,      k0);
            bf16x8 a1 = mkfrag(ysh, crow + 16, k0);
            bf16x8 b0 = mkfrag(ash, wcol,      k0);
            bf16x8 b1 = mkfrag(ash, wcol + 16, k0);
            acc[0][0] = __builtin_amdgcn_mfma_f32_16x16x32_bf16(a0, b0, acc[0][0], 0, 0, 0);
            acc[0][1] = __builtin_amdgcn_mfma_f32_16x16x32_bf16(a0, b1, acc[0][1], 0, 0, 0);
            acc[1][0] = __builtin_amdgcn_mfma_f32_16x16x32_bf16(a1, b0, acc[1][0], 0, 0, 0);
            acc[1][1] = __builtin_amdgcn_mfma_f32_16x16x32_bf16(a1, b1, acc[1][1], 0, 0, 0);
        }
    };

    // prologue: chunk0 -> ra -> LDS buf0; chunk1 -> rb (stays in regs)
    gload(ra, yra, 0);
    gload(rb, yrb, 1);
    ldsw(ra, yra, 0);
    __syncthreads();

    for (int t = 0; t < NCHUNK; t += 2) {
        // even phase: compute chunk t (buf0); ra holds chunk t data
        gstore(ra, t);                            // store-early
        if (t + 2 < NCHUNK) gload(ra, yra, t + 2);
        compute(0);
        ldsw(rb, yrb, 1);                         // chunk t+1 image
        __syncthreads();
        // odd phase: compute chunk t+1 (buf1); rb holds chunk t+1 data
        gstore(rb, t + 1);
        if (t + 3 < NCHUNK) gload(rb, yrb, t + 3);
        compute(1);
        if (t + 2 < NCHUNK) ldsw(ra, yra, 0);     // chunk t+2 image
        __syncthreads();
    }

    // epilogue: D layout col=lane&15, row=(lane>>4)*4+r  [verified m89/m91]
    float* po = out + (size_t)n * CC * VV + w0;
    #pragma unroll
    for (int mt = 0; mt < 2; ++mt)
        #pragma unroll
        for (int nt = 0; nt < 2; ++nt)
            #pragma unroll
            for (int r = 0; r < 4; ++r) {
                int c = mrow * 32 + mt * 16 + kq + r;
                int w = ncol * 32 + nt * 16 + l15;
                po[(size_t)c * VV + w] = acc[mt][nt][r];
            }
}

// K3 (only in tail-fallback mode): copy the A rows whose Acopy slots held y
__global__ __launch_bounds__(256) void k_tailcopy(const float* __restrict__ A,
                                                  float* __restrict__ Acopy,
                                                  size_t baseFloats, size_t count4) {
    size_t i = (size_t)blockIdx.x * 256 + threadIdx.x;
    if (i < count4) {
        f32x4 v = *(const f32x4*)(A + baseFloats + i * 4);
        *(f32x4*)(Acopy + baseFloats + i * 4) = v;
    }
}

extern "C" void kernel_launch(void* const* d_in, const int* in_sizes, int n_in,
                              void* d_out, int out_size, void* d_ws, size_t ws_size,
                              hipStream_t stream) {
    (void)in_sizes; (void)n_in; (void)out_size;
    const float* x = (const float*)d_in[0];
    const float* A = (const float*)d_in[1];
    const float* W = (const float*)d_in[2];
    const float* b = (const float*)d_in[3];
    float* out   = (float*)d_out;
    float* Acopy = out + (size_t)NB * CC * VV;

    const size_t yElems = (size_t)NB * NCHUNK * CC * KB;   // 2,097,152 bf16 = 4 MB
    __bf16* yws;
    int skipTail = 0;
    if (ws_size >= yElems * 2) {
        yws = (__bf16*)d_ws;
    } else {
        skipTail = 1;  // park y in the tail of the A-copy region (rows A[3][8064:])
        yws = (__bf16*)(Acopy + ((size_t)NB * VV * VV - yElems / 2));
    }

    hipLaunchKernelGGL(k_y,    dim3(512),     dim3(256), 0, stream, x, W, b, yws);
    hipLaunchKernelGGL(k_main, dim3(NB * 64), dim3(512), 0, stream, A, yws, out, Acopy, skipTail);
    if (skipTail) {
        size_t base = (size_t)NB * VV * VV - yElems / 2;     // floats
        hipLaunchKernelGGL(k_tailcopy, dim3((unsigned)((yElems / 8 + 255) / 256)), dim3(256),
                           0, stream, A, Acopy, base, yElems / 8);
    }
}